// Round 7
// baseline (221.830 us; speedup 1.0000x reference)
//
#include <hip/hip_runtime.h>
#include <math.h>

#define B_SZ 16384
#define F_N 39
#define V_N 30000
#define D_N 16
#define K_SEL 20
#define FD 624     // F_N * D_N
#define KP0 640    // controller/GEMM0 K padded to multiple of 32
#define NCP 48     // controller GEMM padded N (>= 39, 3 n-tiles of 16)
#define N0 1024
#define N1 512
#define CBR 16     // batch rows per fused-controller block
#define ALD 648    // LDS row stride (u16)

typedef unsigned short u16;
typedef __attribute__((ext_vector_type(8))) short bf16x8;
typedef __attribute__((ext_vector_type(8))) unsigned short u16x8;
typedef __attribute__((ext_vector_type(4))) float f32x4;

__device__ __forceinline__ float bf2f(u16 v) {
    union { unsigned u; float f; } x; x.u = ((unsigned)v) << 16;
    return x.f;
}
// HW packed convert: D[15:0]=bf16(a), D[31:16]=bf16(b), RNE.
__device__ __forceinline__ unsigned cvtpk2(float a, float b) {
    unsigned d;
    asm("v_cvt_pk_bf16_f32 %0, %1, %2" : "=v"(d) : "v"(a), "v"(b));
    return d;
}

#define GLD16(gp, lp) __builtin_amdgcn_global_load_lds( \
    (const __attribute__((address_space(1))) unsigned int*)(gp), \
    (__attribute__((address_space(3))) unsigned int*)(lp), 16, 0, 0)

#define MFMA16(a, b, c) __builtin_amdgcn_mfma_f32_16x16x32_bf16((a), (b), (c), 0, 0, 0)

// ---------------------------------------------------------------------------
// prep (coalesced): [0,134) w0/wc permute via LDS; [134,390) w1 convert;
// 390: bn param vectors.  (outp removed -- no longer exists)
// ---------------------------------------------------------------------------
__global__ __launch_bounds__(256) void prep_all_kernel(
    const float* __restrict__ w0, const float* __restrict__ w1,
    const float* __restrict__ w_c, const float* __restrict__ b_c,
    const float* __restrict__ g_c, const float* __restrict__ be_c,
    u16* __restrict__ w0b, u16* __restrict__ w1b, u16* __restrict__ wcb,
    float* __restrict__ bcp, float* __restrict__ gcp, float* __restrict__ becp)
{
    __shared__ float Lb[8][624];
    const int bid = blockIdx.x;
    const int t   = threadIdx.x;

    if (bid < 134) {                       // w0 (bid<128) or wc permute
        const bool is_w0 = (bid < 128);
        const int r0 = is_w0 ? bid * 8 : (bid - 128) * 8;
        const int nrows_src = is_w0 ? N0 : F_N;
        const float* __restrict__ src = is_w0 ? w0 : w_c;
        u16* __restrict__ dst = is_w0 ? w0b : wcb;

        for (int j = t; j < 8 * 156; j += 256) {
            const int row = j / 156;
            const int c4  = j - row * 156;
            const int n   = r0 + row;
            if (n < nrows_src)
                *(float4*)&Lb[row][c4 * 4] =
                    *(const float4*)&src[(size_t)n * FD + c4 * 4];
        }
        __syncthreads();

        for (int j = t; j < 8 * 320; j += 256) {
            const int row = j / 320;
            const int pr  = j - row * 320;
            const int n   = r0 + row;
            const int k0  = pr * 2;
            float v0 = 0.f, v1 = 0.f;
            if (n < nrows_src) {
                const int d0 = k0 & 15,       f0 = k0 >> 4;
                const int d1 = (k0 + 1) & 15, f1 = (k0 + 1) >> 4;
                if (f0 < F_N) v0 = Lb[row][d0 * F_N + f0];
                if (f1 < F_N) v1 = Lb[row][d1 * F_N + f1];
            }
            *(unsigned*)&dst[(size_t)n * KP0 + k0] = cvtpk2(v0, v1);
        }
        return;
    }
    if (bid < 390) {                       // w1 convert
        const size_t e0 = (size_t)(bid - 134) * 2048 + t * 8;
        float4 v0 = *(const float4*)(w1 + e0);
        float4 v1 = *(const float4*)(w1 + e0 + 4);
        uint4 o = { cvtpk2(v0.x, v0.y), cvtpk2(v0.z, v0.w),
                    cvtpk2(v1.x, v1.y), cvtpk2(v1.z, v1.w) };
        *(uint4*)(w1b + e0) = o;
        return;
    }
    // bid == 390: bn params
    if (t < 3 * NCP) {
        const int which = t / NCP, n = t - which * NCP;
        float v = 0.f;
        if (n < F_N) v = (which == 0) ? b_c[n] : (which == 1) ? g_c[n] : be_c[n];
        ((which == 0) ? bcp : (which == 1) ? gcp : becp)[n] = v;
    }
}

// ---------------------------------------------------------------------------
// Fused controller (proven r3 version, unchanged): gather -> LDS, 16x48 MFMA
// split-K, all-wave reduce, wave-sliced bn/softmax/top-K rank, zb write.
// ---------------------------------------------------------------------------
__global__ __launch_bounds__(256) void fused_controller_kernel(
    const int* __restrict__ x, const float* __restrict__ emb_table,
    const u16* __restrict__ wcb, const float* __restrict__ bcp,
    const float* __restrict__ gcp, const float* __restrict__ becp,
    u16* __restrict__ zb)
{
    __shared__ __align__(16) u16 Al[CBR * ALD];
    __shared__ float vv[CBR][49];
    __shared__ f32x4 part[4][64][3];
    __shared__ float selw[CBR][F_N];

    const int t    = threadIdx.x;
    const int wave = t >> 6;
    const int lane = t & 63;
    const int b0   = blockIdx.x * CBR;

    {
        const int p0 = t, p1 = t + 256, p2 = t + 512;
        const int xi0 = x[b0 * F_N + p0];
        const int xi1 = x[b0 * F_N + p1];
        const int xi2 = (p2 < CBR * F_N) ? x[b0 * F_N + p2] : 0;
        const int pp[3] = { p0, p1, p2 };
        const int xx[3] = { xi0, xi1, xi2 };
        #pragma unroll
        for (int s = 0; s < 3; ++s) {
            const int p = pp[s];
            if (p < CBR * F_N) {
                const int row = p / F_N;
                const int f   = p - row * F_N;
                const float4* src =
                    (const float4*)(emb_table + (size_t)(xx[s] + f * V_N) * D_N);
                float4 v0 = src[0], v1 = src[1], v2 = src[2], v3 = src[3];
                uint4 o0 = { cvtpk2(v0.x, v0.y), cvtpk2(v0.z, v0.w),
                             cvtpk2(v1.x, v1.y), cvtpk2(v1.z, v1.w) };
                uint4 o1 = { cvtpk2(v2.x, v2.y), cvtpk2(v2.z, v2.w),
                             cvtpk2(v3.x, v3.y), cvtpk2(v3.z, v3.w) };
                *(uint4*)&Al[row * ALD + f * D_N]     = o0;
                *(uint4*)&Al[row * ALD + f * D_N + 8] = o1;
            }
        }
    }
    __syncthreads();

    const int m = lane & 15;
    const int q = lane >> 4;
    f32x4 acc0 = {}, acc1 = {}, acc2 = {};
    {
        const u16* ap  = &Al[m * ALD + wave * 160 + q * 8];
        const u16* bp0 = wcb + (size_t)(0  + m) * KP0 + wave * 160 + q * 8;
        const u16* bp1 = wcb + (size_t)(16 + m) * KP0 + wave * 160 + q * 8;
        const u16* bp2 = wcb + (size_t)(32 + m) * KP0 + wave * 160 + q * 8;
        #pragma unroll
        for (int k = 0; k < 5; ++k) {
            bf16x8 af = *(const bf16x8*)ap;
            bf16x8 b0r = *(const bf16x8*)bp0;
            bf16x8 b1r = *(const bf16x8*)bp1;
            bf16x8 b2r = *(const bf16x8*)bp2;
            acc0 = MFMA16(af, b0r, acc0);
            acc1 = MFMA16(af, b1r, acc1);
            acc2 = MFMA16(af, b2r, acc2);
            ap += 32; bp0 += 32; bp1 += 32; bp2 += 32;
        }
    }
    part[wave][lane][0] = acc0;
    part[wave][lane][1] = acc1;
    part[wave][lane][2] = acc2;
    __syncthreads();

    {
        f32x4 r0 = part[0][lane][0] + part[1][lane][0] + part[2][lane][0] + part[3][lane][0];
        f32x4 r1 = part[0][lane][1] + part[1][lane][1] + part[2][lane][1] + part[3][lane][1];
        f32x4 r2 = part[0][lane][2] + part[1][lane][2] + part[2][lane][2] + part[3][lane][2];

        const float rs = rsqrtf(1.0f + 1e-5f);
        if (q == wave) {
            #pragma unroll
            for (int j = 0; j < 3; ++j) {
                const f32x4 a = (j == 0) ? r0 : (j == 1) ? r1 : r2;
                const int n = j * 16 + m;
                const float gn = gcp[n] * rs;
                const float bn = becp[n];
                const float bi = bcp[n];
                #pragma unroll
                for (int r = 0; r < 4; ++r)
                    vv[wave * 4 + r][n] = fmaxf(fmaf(gn, a[r] + bi, bn), 0.f);
            }
        }
    }
    __syncthreads();

    {
        const int row = wave * 4 + (lane >> 4);
        const int fl  = lane & 15;
        float e[3] = {0.f, 0.f, 0.f};
        float mloc = -1e30f;
        #pragma unroll
        for (int it = 0; it < 3; ++it) {
            const int f = fl + 16 * it;
            if (f < F_N) { e[it] = vv[row][f]; mloc = fmaxf(mloc, e[it]); }
        }
        mloc = fmaxf(mloc, __shfl_xor(mloc, 1, 64));
        mloc = fmaxf(mloc, __shfl_xor(mloc, 2, 64));
        mloc = fmaxf(mloc, __shfl_xor(mloc, 4, 64));
        mloc = fmaxf(mloc, __shfl_xor(mloc, 8, 64));
        float sloc = 0.f;
        #pragma unroll
        for (int it = 0; it < 3; ++it) {
            const int f = fl + 16 * it;
            if (f < F_N) { e[it] = expf(e[it] - mloc); sloc += e[it]; }
        }
        sloc += __shfl_xor(sloc, 1, 64);
        sloc += __shfl_xor(sloc, 2, 64);
        sloc += __shfl_xor(sloc, 4, 64);
        sloc += __shfl_xor(sloc, 8, 64);
        const float inv = 1.f / sloc;
        #pragma unroll
        for (int it = 0; it < 3; ++it) {
            const int f = fl + 16 * it;
            if (f < F_N) vv[row][f] = e[it];
        }

        int rank[3] = {};
        for (int gg = 0; gg < F_N; ++gg) {
            const float o = vv[row][gg];
            #pragma unroll
            for (int it = 0; it < 3; ++it) {
                const int f = fl + 16 * it;
                if (f < F_N)
                    rank[it] += (o > e[it] || (o == e[it] && gg < f)) ? 1 : 0;
            }
        }
        #pragma unroll
        for (int it = 0; it < 3; ++it) {
            const int f = fl + 16 * it;
            if (f < F_N)
                selw[row][f] = (rank[it] < K_SEL) ? e[it] * inv : 0.f;
        }
    }
    __syncthreads();

    for (int gp = t; gp < CBR * 40; gp += 256) {
        const int row  = gp / 40;
        const int slot = gp - row * 40;
        u16* dst = zb + (size_t)(b0 + row) * KP0 + slot * D_N;
        uint4 o0 = {0u,0u,0u,0u}, o1 = {0u,0u,0u,0u};
        if (slot < F_N) {
            const float w = selw[row][slot];
            u16x8 a0 = *(u16x8*)&Al[row * ALD + slot * D_N];
            u16x8 a1 = *(u16x8*)&Al[row * ALD + slot * D_N + 8];
            o0 = (uint4){ cvtpk2(bf2f(a0[0]) * w, bf2f(a0[1]) * w),
                          cvtpk2(bf2f(a0[2]) * w, bf2f(a0[3]) * w),
                          cvtpk2(bf2f(a0[4]) * w, bf2f(a0[5]) * w),
                          cvtpk2(bf2f(a0[6]) * w, bf2f(a0[7]) * w) };
            o1 = (uint4){ cvtpk2(bf2f(a1[0]) * w, bf2f(a1[1]) * w),
                          cvtpk2(bf2f(a1[2]) * w, bf2f(a1[3]) * w),
                          cvtpk2(bf2f(a1[4]) * w, bf2f(a1[5]) * w),
                          cvtpk2(bf2f(a1[6]) * w, bf2f(a1[7]) * w) };
        }
        *(uint4*)dst       = o0;
        *(uint4*)(dst + 8) = o1;
    }
}

// ---------------------------------------------------------------------------
// Fused MLP: per block (64 batch rows, 8 waves = 2m x 4n):
//   for nt in 0..3 (h0 col-chunks of 256):
//     phase A: h0c = relu(bn0(zb[64x640] @ w0b[nt-chunk]^T)) -- 3-stage
//              counted-vmcnt pipeline (waves 0-3 stage A+B: vmcnt(3);
//              waves 4-7 stage B only: vmcnt(2)), 20 K-steps.
//     h0c -> LDS bf16 [64][264-stride] (cvt_pk).
//     phase B: acc1[64x512] += h0c @ w1b[:, nt-chunk]^T, K=256, 8 K-steps,
//              same pipeline (vmcnt(4)); A-frags ds_read from H0
//              (stride 264 u16 -> ~conflict-free); phase-B prologue issued
//              BEFORE the h0 epilogue so HBM/L2 latency hides under it.
//   epilogue: bn1/relu, dot w_out, shuffle+LDS reduce, sigmoid -> out.
// h0 never touches HBM (removes 67 MB round-trip); no atomics; K-accum
// order identical to the split version (bit-identical numerics).
// LDS: 96 KB arena + 33 KB H0 + 1 KB red = 130 KB -> 1 block/CU; grid 256.
// ---------------------------------------------------------------------------
__global__ __launch_bounds__(512) void fused_mlp_kernel(
    const u16* __restrict__ Azb, const u16* __restrict__ W0,
    const u16* __restrict__ W1,
    const float* __restrict__ b0v, const float* __restrict__ g0v,
    const float* __restrict__ be0v,
    const float* __restrict__ b1v, const float* __restrict__ g1v,
    const float* __restrict__ be1v,
    const float* __restrict__ wov, const float* __restrict__ bov,
    float* __restrict__ out)
{
    __shared__ __align__(16) u16 SM[3 * 16384];   // 96 KB staging arena
    __shared__ __align__(16) u16 H0[64 * 264];    // 33 KB h0 chunk
    __shared__ float red[4][64];

    const int t    = threadIdx.x;
    const int lane = t & 63;
    const int wave = t >> 6;
    const int wm = wave >> 2, wn = wave & 3;
    const int q = lane >> 4, lr16 = lane & 15;
    const int brow = blockIdx.x * 64;

    const int srow = t >> 2;                      // staging row
    const int cC   = (t & 3) ^ ((t >> 3) & 3);    // staging chunk swizzle
    const int dA  = t * 8;
    const int dB0 = 2048 + t * 8;
    const int dB1 = 2048 + (t + 512) * 8;

    const u16* gAz = Azb + (size_t)(brow + srow) * KP0 + cC * 8;  // t<256 use

    int aoffA[2], boffA[4], aoffB[2], boffB[8];
    #pragma unroll
    for (int i = 0; i < 2; ++i) {
        const int ra = wm * 32 + i * 16 + lr16;
        aoffA[i] = ra * 32 + ((q ^ ((ra >> 1) & 3)) * 8);
        aoffB[i] = ra * 264 + q * 8;
    }
    #pragma unroll
    for (int j = 0; j < 4; ++j) {
        const int rb = wn * 64 + j * 16 + lr16;
        boffA[j] = 2048 + rb * 32 + ((q ^ ((rb >> 1) & 3)) * 8);
    }
    #pragma unroll
    for (int j = 0; j < 8; ++j) {
        const int rb = wn * 128 + j * 16 + lr16;
        boffB[j] = rb * 32 + ((q ^ ((rb >> 1) & 3)) * 8);
    }

    f32x4 acc1[2][8] = {};
    const float rs = rsqrtf(1.0f + 1e-5f);

    for (int nt = 0; nt < 4; ++nt) {
        // ================= phase A =================
        f32x4 acc0[2][4] = {};
        const u16* pA  = gAz;
        const u16* pB0 = W0 + (size_t)(nt * 256 + srow)       * KP0 + cC * 8;
        const u16* pB1 = W0 + (size_t)(nt * 256 + srow + 128) * KP0 + cC * 8;

        // prologue: k-steps 0,1 -> slots 0,1 (safe: slots 0,1 free here)
        if (t < 256) GLD16(pA, SM + dA);
        GLD16(pB0, SM + dB0);
        GLD16(pB1, SM + dB1);
        pA += 32; pB0 += 32; pB1 += 32;
        if (t < 256) GLD16(pA, SM + 16384 + dA);
        GLD16(pB0, SM + 16384 + dB0);
        GLD16(pB1, SM + 16384 + dB1);
        pA += 32; pB0 += 32; pB1 += 32;

        int cur = 0, stg = 2;
        for (int it = 0; it < 19; ++it) {
            if (t < 256) { asm volatile("s_waitcnt vmcnt(3)" ::: "memory"); }
            else         { asm volatile("s_waitcnt vmcnt(2)" ::: "memory"); }
            __builtin_amdgcn_s_barrier();
            __builtin_amdgcn_sched_barrier(0);
            const u16* sc = SM + cur * 16384;
            bf16x8 a0 = *(const bf16x8*)(sc + aoffA[0]);
            bf16x8 a1 = *(const bf16x8*)(sc + aoffA[1]);
            bf16x8 f0 = *(const bf16x8*)(sc + boffA[0]);
            bf16x8 f1 = *(const bf16x8*)(sc + boffA[1]);
            bf16x8 f2 = *(const bf16x8*)(sc + boffA[2]);
            bf16x8 f3 = *(const bf16x8*)(sc + boffA[3]);
            if (it + 2 < 20) {
                u16* ss = SM + stg * 16384;
                if (t < 256) GLD16(pA, ss + dA);
                GLD16(pB0, ss + dB0);
                GLD16(pB1, ss + dB1);
                pA += 32; pB0 += 32; pB1 += 32;
            }
            asm volatile("s_waitcnt lgkmcnt(0)" ::: "memory");
            __builtin_amdgcn_sched_barrier(0);
            __builtin_amdgcn_s_setprio(1);
            acc0[0][0] = MFMA16(a0, f0, acc0[0][0]);
            acc0[0][1] = MFMA16(a0, f1, acc0[0][1]);
            acc0[0][2] = MFMA16(a0, f2, acc0[0][2]);
            acc0[0][3] = MFMA16(a0, f3, acc0[0][3]);
            acc0[1][0] = MFMA16(a1, f0, acc0[1][0]);
            acc0[1][1] = MFMA16(a1, f1, acc0[1][1]);
            acc0[1][2] = MFMA16(a1, f2, acc0[1][2]);
            acc0[1][3] = MFMA16(a1, f3, acc0[1][3]);
            __builtin_amdgcn_s_setprio(0);
            cur = (cur == 2) ? 0 : cur + 1;
            stg = (stg == 2) ? 0 : stg + 1;
        }
        // peel it=19 (cur == 1)
        asm volatile("s_waitcnt vmcnt(0)" ::: "memory");
        __builtin_amdgcn_s_barrier();
        __builtin_amdgcn_sched_barrier(0);
        {
            const u16* sc = SM + 16384;
            bf16x8 a0 = *(const bf16x8*)(sc + aoffA[0]);
            bf16x8 a1 = *(const bf16x8*)(sc + aoffA[1]);
            bf16x8 f0 = *(const bf16x8*)(sc + boffA[0]);
            bf16x8 f1 = *(const bf16x8*)(sc + boffA[1]);
            bf16x8 f2 = *(const bf16x8*)(sc + boffA[2]);
            bf16x8 f3 = *(const bf16x8*)(sc + boffA[3]);
            asm volatile("s_waitcnt lgkmcnt(0)" ::: "memory");
            __builtin_amdgcn_sched_barrier(0);
            __builtin_amdgcn_s_setprio(1);
            acc0[0][0] = MFMA16(a0, f0, acc0[0][0]);
            acc0[0][1] = MFMA16(a0, f1, acc0[0][1]);
            acc0[0][2] = MFMA16(a0, f2, acc0[0][2]);
            acc0[0][3] = MFMA16(a0, f3, acc0[0][3]);
            acc0[1][0] = MFMA16(a1, f0, acc0[1][0]);
            acc0[1][1] = MFMA16(a1, f1, acc0[1][1]);
            acc0[1][2] = MFMA16(a1, f2, acc0[1][2]);
            acc0[1][3] = MFMA16(a1, f3, acc0[1][3]);
            __builtin_amdgcn_s_setprio(0);
        }

        // phase-B prologue: ks=0 -> slot0, ks=1 -> slot2 (slot 1 in use by
        // peel; slots 0/2 reads all completed before the peel barrier).
        // Issued BEFORE the h0 epilogue so load latency hides under it.
        const u16* pC = W1 + (size_t)srow * N0 + nt * 256 + cC * 8;
        {
            GLD16(pC,               SM + t * 8);
            GLD16(pC + 131072,      SM + (t + 512) * 8);
            GLD16(pC + 262144,      SM + (t + 1024) * 8);
            GLD16(pC + 393216,      SM + (t + 1536) * 8);
            u16* s2 = SM + 2 * 16384;
            GLD16(pC + 32,          s2 + t * 8);
            GLD16(pC + 131072 + 32, s2 + (t + 512) * 8);
            GLD16(pC + 262144 + 32, s2 + (t + 1024) * 8);
            GLD16(pC + 393216 + 32, s2 + (t + 1536) * 8);
        }

        // h0 chunk epilogue -> H0 bf16
        #pragma unroll
        for (int j = 0; j < 4; ++j) {
            const int n = nt * 256 + wn * 64 + j * 16 + lr16;
            const float gg = g0v[n] * rs;
            const float bb = be0v[n];
            const float bi = b0v[n];
            const int colL = wn * 64 + j * 16 + lr16;
            #pragma unroll
            for (int i = 0; i < 2; ++i) {
                const int mlb = wm * 32 + i * 16 + q * 4;
                float v0 = fmaxf(fmaf(gg, acc0[i][j][0] + bi, bb), 0.f);
                float v1 = fmaxf(fmaf(gg, acc0[i][j][1] + bi, bb), 0.f);
                float v2 = fmaxf(fmaf(gg, acc0[i][j][2] + bi, bb), 0.f);
                float v3 = fmaxf(fmaf(gg, acc0[i][j][3] + bi, bb), 0.f);
                unsigned pa = cvtpk2(v0, v1);
                unsigned pb = cvtpk2(v2, v3);
                H0[(mlb + 0) * 264 + colL] = (u16)pa;
                H0[(mlb + 1) * 264 + colL] = (u16)(pa >> 16);
                H0[(mlb + 2) * 264 + colL] = (u16)pb;
                H0[(mlb + 3) * 264 + colL] = (u16)(pb >> 16);
            }
        }
        asm volatile("s_waitcnt lgkmcnt(0)" ::: "memory");
        __builtin_amdgcn_s_barrier();

        // ================= phase B =================
        const u16* pCk = pC + 64;
        int cb = 0, sb = 1;          // slot sequence 0,2,1,... (descending)
        for (int ks = 0; ks < 7; ++ks) {
            asm volatile("s_waitcnt vmcnt(4)" ::: "memory");
            __builtin_amdgcn_s_barrier();
            __builtin_amdgcn_sched_barrier(0);
            const u16* sc = SM + cb * 16384;
            bf16x8 a0 = *(const bf16x8*)(&H0[aoffB[0] + ks * 32]);
            bf16x8 a1 = *(const bf16x8*)(&H0[aoffB[1] + ks * 32]);
            bf16x8 f0 = *(const bf16x8*)(sc + boffB[0]);
            bf16x8 f1 = *(const bf16x8*)(sc + boffB[1]);
            bf16x8 f2 = *(const bf16x8*)(sc + boffB[2]);
            bf16x8 f3 = *(const bf16x8*)(sc + boffB[3]);
            bf16x8 f4 = *(const bf16x8*)(sc + boffB[4]);
            bf16x8 f5 = *(const bf16x8*)(sc + boffB[5]);
            bf16x8 f6 = *(const bf16x8*)(sc + boffB[6]);
            bf16x8 f7 = *(const bf16x8*)(sc + boffB[7]);
            if (ks + 2 < 8) {
                u16* ss = SM + sb * 16384;
                GLD16(pCk,          ss + t * 8);
                GLD16(pCk + 131072, ss + (t + 512) * 8);
                GLD16(pCk + 262144, ss + (t + 1024) * 8);
                GLD16(pCk + 393216, ss + (t + 1536) * 8);
                pCk += 32;
            }
            asm volatile("s_waitcnt lgkmcnt(0)" ::: "memory");
            __builtin_amdgcn_sched_barrier(0);
            __builtin_amdgcn_s_setprio(1);
            acc1[0][0] = MFMA16(a0, f0, acc1[0][0]);
            acc1[0][1] = MFMA16(a0, f1, acc1[0][1]);
            acc1[0][2] = MFMA16(a0, f2, acc1[0][2]);
            acc1[0][3] = MFMA16(a0, f3, acc1[0][3]);
            acc1[0][4] = MFMA16(a0, f4, acc1[0][4]);
            acc1[0][5] = MFMA16(a0, f5, acc1[0][5]);
            acc1[0][6] = MFMA16(a0, f6, acc1[0][6]);
            acc1[0][7] = MFMA16(a0, f7, acc1[0][7]);
            acc1[1][0] = MFMA16(a1, f0, acc1[1][0]);
            acc1[1][1] = MFMA16(a1, f1, acc1[1][1]);
            acc1[1][2] = MFMA16(a1, f2, acc1[1][2]);
            acc1[1][3] = MFMA16(a1, f3, acc1[1][3]);
            acc1[1][4] = MFMA16(a1, f4, acc1[1][4]);
            acc1[1][5] = MFMA16(a1, f5, acc1[1][5]);
            acc1[1][6] = MFMA16(a1, f6, acc1[1][6]);
            acc1[1][7] = MFMA16(a1, f7, acc1[1][7]);
            __builtin_amdgcn_s_setprio(0);
            cb = (cb == 0) ? 2 : cb - 1;
            sb = (sb == 0) ? 2 : sb - 1;
        }
        // peel ks=7 (cb == 2)
        asm volatile("s_waitcnt vmcnt(0)" ::: "memory");
        __builtin_amdgcn_s_barrier();
        __builtin_amdgcn_sched_barrier(0);
        {
            const u16* sc = SM + 2 * 16384;
            bf16x8 a0 = *(const bf16x8*)(&H0[aoffB[0] + 7 * 32]);
            bf16x8 a1 = *(const bf16x8*)(&H0[aoffB[1] + 7 * 32]);
            bf16x8 f0 = *(const bf16x8*)(sc + boffB[0]);
            bf16x8 f1 = *(const bf16x8*)(sc + boffB[1]);
            bf16x8 f2 = *(const bf16x8*)(sc + boffB[2]);
            bf16x8 f3 = *(const bf16x8*)(sc + boffB[3]);
            bf16x8 f4 = *(const bf16x8*)(sc + boffB[4]);
            bf16x8 f5 = *(const bf16x8*)(sc + boffB[5]);
            bf16x8 f6 = *(const bf16x8*)(sc + boffB[6]);
            bf16x8 f7 = *(const bf16x8*)(sc + boffB[7]);
            asm volatile("s_waitcnt lgkmcnt(0)" ::: "memory");
            __builtin_amdgcn_sched_barrier(0);
            __builtin_amdgcn_s_setprio(1);
            acc1[0][0] = MFMA16(a0, f0, acc1[0][0]);
            acc1[0][1] = MFMA16(a0, f1, acc1[0][1]);
            acc1[0][2] = MFMA16(a0, f2, acc1[0][2]);
            acc1[0][3] = MFMA16(a0, f3, acc1[0][3]);
            acc1[0][4] = MFMA16(a0, f4, acc1[0][4]);
            acc1[0][5] = MFMA16(a0, f5, acc1[0][5]);
            acc1[0][6] = MFMA16(a0, f6, acc1[0][6]);
            acc1[0][7] = MFMA16(a0, f7, acc1[0][7]);
            acc1[1][0] = MFMA16(a1, f0, acc1[1][0]);
            acc1[1][1] = MFMA16(a1, f1, acc1[1][1]);
            acc1[1][2] = MFMA16(a1, f2, acc1[1][2]);
            acc1[1][3] = MFMA16(a1, f3, acc1[1][3]);
            acc1[1][4] = MFMA16(a1, f4, acc1[1][4]);
            acc1[1][5] = MFMA16(a1, f5, acc1[1][5]);
            acc1[1][6] = MFMA16(a1, f6, acc1[1][6]);
            acc1[1][7] = MFMA16(a1, f7, acc1[1][7]);
            __builtin_amdgcn_s_setprio(0);
        }
    }

    // ================= final epilogue =================
    float s[2][4] = {};
    #pragma unroll
    for (int j = 0; j < 8; ++j) {
        const int n1 = wn * 128 + j * 16 + lr16;
        const float wv = wov[n1];
        const float gg = g1v[n1] * rs;
        const float bb = be1v[n1];
        const float bi = b1v[n1];
        #pragma unroll
        for (int i = 0; i < 2; ++i)
            #pragma unroll
            for (int r = 0; r < 4; ++r) {
                float v = fmaxf(fmaf(gg, acc1[i][j][r] + bi, bb), 0.f);
                s[i][r] = fmaf(v, wv, s[i][r]);
            }
    }
    #pragma unroll
    for (int i = 0; i < 2; ++i)
        #pragma unroll
        for (int r = 0; r < 4; ++r) {
            float v = s[i][r];
            v += __shfl_xor(v, 1, 64);
            v += __shfl_xor(v, 2, 64);
            v += __shfl_xor(v, 4, 64);
            v += __shfl_xor(v, 8, 64);
            s[i][r] = v;
        }
    if (lr16 == 0) {
        #pragma unroll
        for (int i = 0; i < 2; ++i)
            #pragma unroll
            for (int r = 0; r < 4; ++r)
                red[wn][wm * 32 + i * 16 + q * 4 + r] = s[i][r];
    }
    __syncthreads();
    if (t < 64) {
        const float v = red[0][t] + red[1][t] + red[2][t] + red[3][t] + bov[0];
        out[brow + t] = 1.f / (1.f + expf(-v));
    }
}

// ---------------------------------------------------------------------------
extern "C" void kernel_launch(void* const* d_in, const int* in_sizes, int n_in,
                              void* d_out, int out_size, void* d_ws, size_t ws_size,
                              hipStream_t stream)
{
    const int*   x     = (const int*)  d_in[0];
    const float* emb   = (const float*)d_in[1];
    const float* w_c   = (const float*)d_in[2];
    const float* b_c   = (const float*)d_in[3];
    const float* g_c   = (const float*)d_in[4];
    const float* be_c  = (const float*)d_in[5];
    const float* w0    = (const float*)d_in[6];
    const float* b0    = (const float*)d_in[7];
    const float* g0    = (const float*)d_in[8];
    const float* be0   = (const float*)d_in[9];
    const float* w1    = (const float*)d_in[10];
    const float* b1    = (const float*)d_in[11];
    const float* g1    = (const float*)d_in[12];
    const float* be1   = (const float*)d_in[13];
    const float* w_out = (const float*)d_in[14];
    const float* b_out = (const float*)d_in[15];
    float* out = (float*)d_out;

    // workspace layout (~23 MB; h0b and outp eliminated)
    u16*   zb    = (u16*)d_ws;                          // B*640*2 = 20.97 MB
    u16*   w0b   = zb  + (size_t)B_SZ * KP0;            // 1.31 MB
    u16*   w1b   = w0b + (size_t)N0 * KP0;              // 1.05 MB
    u16*   wcb   = w1b + (size_t)N1 * N0;               // 0.06 MB
    float* bcp   = (float*)(wcb + (size_t)NCP * KP0);
    float* gcp   = bcp + NCP;
    float* becp  = gcp + NCP;

    prep_all_kernel<<<391, 256, 0, stream>>>(
        w0, w1, w_c, b_c, g_c, be_c, w0b, w1b, wcb, bcp, gcp, becp);

    fused_controller_kernel<<<B_SZ / CBR, 256, 0, stream>>>(
        x, emb, wcb, bcp, gcp, becp, zb);

    fused_mlp_kernel<<<B_SZ / 64, 512, 0, stream>>>(
        zb, w0b, w1b, b0, g0, be0, b1, g1, be1, w_out, b_out, out);
}